// Round 13
// baseline (128.521 us; speedup 1.0000x reference)
//
#include <hip/hip_runtime.h>
#include <hip/hip_bf16.h>
#include <math.h>
#include <string.h>

typedef __attribute__((ext_vector_type(8))) short bf16x8;
typedef __attribute__((ext_vector_type(4))) float f32x4;
typedef __attribute__((ext_vector_type(16))) float f32x16;
typedef __attribute__((ext_vector_type(4))) unsigned int u32x4;

#define BLK 256

// All-32x32x16 pipeline. Batch rows in lane&31 everywhere. (Body = R11/R12.)
// R13: occupancy 2 -> 4 blocks/CU (16 waves/CU). R12's counters showed
// VALUBusy 57% / MfmaUtil 18% / no spill / no conflicts at 2 waves/SIMD:
// VALU-issue-bound with exposed dependency bubbles -> more waves to fill them.
//
// ws layout:
//   [0, 4096)      : W1 Phase-A A-fragments: 4 tiles x 64 lanes x 8 bf16.
//   [4096, 20480)  : W21/W22 GEMM2 A-fragments, frag F = mat*8 + kt:
//                    value = W[n2 = l&31][k = 32t+16c+4*(l>>5)+(j&3)+8*(j>>2)]

__device__ __forceinline__ unsigned int rne_bf16_bits(float w) {
    unsigned int u = __builtin_bit_cast(unsigned int, w);
    u += 0x7fffu + ((u >> 16) & 1u);
    return u >> 16;
}
__device__ __forceinline__ float bf16_to_f32(unsigned int bits) {
    return __builtin_bit_cast(float, bits << 16);
}
__device__ __forceinline__ unsigned int pk_bf16(float lo, float hi) {
    __hip_bfloat162 bp = __float22bfloat162_rn(make_float2(lo, hi));
    unsigned int r; memcpy(&r, &bp, 4);
    return r;                                     // lo -> low 16, hi -> high 16
}

__global__ void setup_kernel(const float* __restrict__ W1, const float* __restrict__ b1,
                             const float* __restrict__ W21, const float* __restrict__ W22,
                             unsigned short* __restrict__ w1f, unsigned short* __restrict__ frg)
{
    int t = blockIdx.x * blockDim.x + threadIdx.x;   // 0..4095
    if (t < 2048) {  // W1 Phase-A table
        int e = t;
        int tt = e >> 9, l = (e >> 3) & 63, j = e & 7;
        int n = tt * 32 + (l & 31), h = l >> 5;
        unsigned short v = 0;
        float src = 0.0f; bool have = false;
        if (j < 5)       { src = W1[n * 5 + j]; have = true; }
        else if (j == 5) { src = b1[n];         have = true; }
        if (have) {
            unsigned int hi = rne_bf16_bits(src);
            if (h == 0) v = (unsigned short)hi;
            else        v = (unsigned short)rne_bf16_bits(src - bf16_to_f32(hi));
        }
        w1f[e] = v;
    }
    for (int e = t; e < 16 * 64 * 8; e += 4096) {    // GEMM2 table (8192 ushorts)
        int F = e >> 9, l = (e >> 3) & 63, j = e & 7;
        int mat = F >> 3, kt = F & 7;
        int tt = kt >> 1, c = kt & 1;
        int n2 = l & 31, h = l >> 5;
        int k = 32 * tt + 16 * c + 4 * h + (j & 3) + 8 * (j >> 2);
        const float* W = mat ? W22 : W21;
        frg[e] = (unsigned short)rne_bf16_bits(W[n2 * 128 + k]);
    }
}

// 1024 blocks (4/CU resident, 16 waves/CU), block = 4 waves = 512 rows;
// wave = 4 iters x 32 rows.
__global__ __launch_bounds__(BLK, 4) void barriernet_kernel(
    const float* __restrict__ x,
    const float* __restrict__ mean, const float* __restrict__ stdv,
    const float* __restrict__ b21, const float* __restrict__ b22,
    const float* __restrict__ W31, const float* __restrict__ b31,
    const float* __restrict__ W32, const float* __restrict__ b32,
    const u32x4* __restrict__ w1fg, const u32x4* __restrict__ frg,
    float* __restrict__ out, int zero)
{
    __shared__ u32x4 ldsF[1024];    // 16 GEMM2 frags x 64 lanes

    const int tid = threadIdx.x;
    #pragma unroll
    for (int i = 0; i < 4; ++i) ldsF[tid + i * BLK] = frg[tid + i * BLK];

    const int lane = tid & 63;
    const int wave = tid >> 6;
    const int R    = lane & 31;     // batch row within tile
    const int h    = lane >> 5;     // K-half / out-neuron offset bit

    // W1 Phase-A A-fragments: register-resident (16 VGPRs).
    u32x4 w1f[4];
    #pragma unroll
    for (int t = 0; t < 4; ++t) w1f[t] = w1fg[t * 64 + lane];

    // Bias / head vectors in out-neuron register order.
    f32x4 bc21[4], bc22[4], wh31[4], wh32[4];
    #pragma unroll
    for (int rq = 0; rq < 4; ++rq) {
        bc21[rq] = *(const f32x4*)(b21 + 8 * rq + 4 * h);
        bc22[rq] = *(const f32x4*)(b22 + 8 * rq + 4 * h);
        wh31[rq] = *(const f32x4*)(W31 + 8 * rq + 4 * h);
        wh32[rq] = *(const f32x4*)(W32 + 8 * rq + 4 * h);
    }

    float sm_s[5], sm_m[5];
    #pragma unroll
    for (int f = 0; f < 5; ++f) { sm_s[f] = stdv[f]; sm_m[f] = mean[f]; }
    const float b31s = b31[0], b32s = b32[0];

    __syncthreads();

    const size_t wrow0 = (size_t)blockIdx.x * 512 + wave * 128;

    // x prefetch for iter 0 (row wrow0 + R; 2x redundancy across halves)
    float4 xc4; float xc1;
    {
        const float* p = x + (wrow0 + R) * 5;
        xc4 = *(const float4*)p; xc1 = p[4];
    }

    #pragma unroll 1
    for (int it = 0; it < 4; ++it) {
        const int itn = (it < 3) ? it + 1 : 3;
        const float* pn = x + (wrow0 + itn * 32 + R) * 5;
        float4 xn4 = *(const float4*)pn;
        float  xn1 = pn[4];

        const float xf[5] = { xc4.x, xc4.y, xc4.z, xc4.w, xc1 };

        // ---- Phase-A B-fragment: {bf16(x0..x4), 1.0, 0, 0} in both halves ----
        u32x4 xd;
        xd[0] = pk_bf16(xf[0], xf[1]);
        xd[1] = pk_bf16(xf[2], xf[3]);
        xd[2] = pk_bf16(xf[4], 1.0f);
        xd[3] = 0u;
        const bf16x8 xb = __builtin_bit_cast(bf16x8, xd);

        // ---- Phase A: 4 MFMAs (32x32x16); D_t regs ARE GEMM2 B-fragments ----
        unsigned int au[8][4];
        #pragma unroll
        for (int t = 0; t < 4; ++t) {
            f32x16 z = {};
            f32x16 D = __builtin_amdgcn_mfma_f32_32x32x16_bf16(
                __builtin_bit_cast(bf16x8, w1f[t]), xb, z, 0, 0, 0);
            #pragma unroll
            for (int c = 0; c < 2; ++c)
                #pragma unroll
                for (int d = 0; d < 4; ++d)
                    au[2 * t + c][d] = pk_bf16(fmaxf(D[8 * c + 2 * d],     0.0f),
                                               fmaxf(D[8 * c + 2 * d + 1], 0.0f));
        }

        // ---- GEMM2: 16 MFMAs (32x32x16), W2 A-frags from LDS ----
        f32x16 acc21, acc22;
        #pragma unroll
        for (int rq = 0; rq < 4; ++rq)
            #pragma unroll
            for (int r = 0; r < 4; ++r) {
                acc21[rq * 4 + r] = bc21[rq][r];
                acc22[rq * 4 + r] = bc22[rq][r];
            }
        const int fz = it * zero;                  // anti-hoist for LDS reads
        #pragma unroll
        for (int kt = 0; kt < 8; ++kt) {
            u32x4 t4 = { au[kt][0], au[kt][1], au[kt][2], au[kt][3] };
            const bf16x8 b = __builtin_bit_cast(bf16x8, t4);
            const bf16x8 wa21 = __builtin_bit_cast(bf16x8, ldsF[kt * 64 + lane + fz]);
            const bf16x8 wa22 = __builtin_bit_cast(bf16x8, ldsF[(8 + kt) * 64 + lane + fz]);
            acc21 = __builtin_amdgcn_mfma_f32_32x32x16_bf16(wa21, b, acc21, 0, 0, 0);
            acc22 = __builtin_amdgcn_mfma_f32_32x32x16_bf16(wa22, b, acc22, 0, 0, 0);
        }

        // ---- Heads: 16 lane-local FMAs each + one cross-half shuffle ----
        float s31 = 0.0f, s32 = 0.0f;
        #pragma unroll
        for (int rq = 0; rq < 4; ++rq)
            #pragma unroll
            for (int r = 0; r < 4; ++r) {
                s31 = fmaf(fmaxf(acc21[rq * 4 + r], 0.0f), wh31[rq][r], s31);
                s32 = fmaf(fmaxf(acc22[rq * 4 + r], 0.0f), wh32[rq][r], s32);
            }
        s31 += __shfl_xor(s31, 32);
        s32 += __shfl_xor(s32, 32);

        // ---- Epilogue (row R; lanes 0-31 store) ----
        const float x31 = s31 + b31s;
        const float z   = s32 + b32s;
        const float x32 = 4.0f / (1.0f + __expf(-z));
        float x0[5];
        #pragma unroll
        for (int f = 0; f < 5; ++f) x0[f] = fmaf(xf[f], sm_s[f], sm_m[f]);
        const float h_ineq = (x0[1] - x0[3]) + x32 * (x0[0] - x0[2] - 1.8f * x0[3]);
        const float u_unc  = -x31;
        const float u      = (1.8f * u_unc <= h_ineq) ? u_unc : (h_ineq / 1.8f);
        if (lane < 32)
            out[wrow0 + it * 32 + R] = u;

        xc4 = xn4; xc1 = xn1;
    }
}

extern "C" void kernel_launch(void* const* d_in, const int* in_sizes, int n_in,
                              void* d_out, int out_size, void* d_ws, size_t ws_size,
                              hipStream_t stream) {
    const float* x    = (const float*)d_in[0];
    const float* mean = (const float*)d_in[1];
    const float* stdv = (const float*)d_in[2];
    const float* W1   = (const float*)d_in[3];
    const float* b1   = (const float*)d_in[4];
    const float* W21  = (const float*)d_in[5];
    const float* b21  = (const float*)d_in[6];
    const float* W22  = (const float*)d_in[7];
    const float* b22  = (const float*)d_in[8];
    const float* W31  = (const float*)d_in[9];
    const float* b31  = (const float*)d_in[10];
    const float* W32  = (const float*)d_in[11];
    const float* b32  = (const float*)d_in[12];
    float* out = (float*)d_out;

    unsigned short* w1f = (unsigned short*)d_ws;
    unsigned short* frg = (unsigned short*)((char*)d_ws + 4096);

    setup_kernel<<<16, 256, 0, stream>>>(W1, b1, W21, W22, w1f, frg);

    // 524288 rows / 512 rows-per-block = 1024 blocks (4/CU resident)
    barriernet_kernel<<<1024, BLK, 0, stream>>>(
        x, mean, stdv, b21, b22, W31, b31, W32, b32,
        (const u32x4*)w1f, (const u32x4*)frg, out, /*zero=*/0);
}

// Round 14
// 102.685 us; speedup vs baseline: 1.2516x; 1.2516x over previous
//
#include <hip/hip_runtime.h>
#include <hip/hip_bf16.h>
#include <math.h>
#include <string.h>

typedef __attribute__((ext_vector_type(8))) short bf16x8;
typedef __attribute__((ext_vector_type(4))) float f32x4;
typedef __attribute__((ext_vector_type(16))) float f32x16;
typedef __attribute__((ext_vector_type(4))) unsigned int u32x4;

#define BLK 256

// All-32x32x16 pipeline. Batch rows in lane&31 everywhere. (Body = R12/R13.)
// R14: __launch_bounds__(256,3). R13's (256,4) cut the unified VGPR+AGPR
// budget to 128 < the ~136 the body needs -> 150 MB scratch spill (FETCH
// 103 MB / WRITE 53 MB). At 3 waves/EU the budget is ~170: no spill, and
// +50% TLP over R12's 2 waves/EU (which showed VALUBusy 57%, 25% idle).
//
// ws layout:
//   [0, 4096)      : W1 Phase-A A-fragments: 4 tiles x 64 lanes x 8 bf16.
//   [4096, 20480)  : W21/W22 GEMM2 A-fragments, frag F = mat*8 + kt:
//                    value = W[n2 = l&31][k = 32t+16c+4*(l>>5)+(j&3)+8*(j>>2)]

__device__ __forceinline__ unsigned int rne_bf16_bits(float w) {
    unsigned int u = __builtin_bit_cast(unsigned int, w);
    u += 0x7fffu + ((u >> 16) & 1u);
    return u >> 16;
}
__device__ __forceinline__ float bf16_to_f32(unsigned int bits) {
    return __builtin_bit_cast(float, bits << 16);
}
__device__ __forceinline__ unsigned int pk_bf16(float lo, float hi) {
    __hip_bfloat162 bp = __float22bfloat162_rn(make_float2(lo, hi));
    unsigned int r; memcpy(&r, &bp, 4);
    return r;                                     // lo -> low 16, hi -> high 16
}

__global__ void setup_kernel(const float* __restrict__ W1, const float* __restrict__ b1,
                             const float* __restrict__ W21, const float* __restrict__ W22,
                             unsigned short* __restrict__ w1f, unsigned short* __restrict__ frg)
{
    int t = blockIdx.x * blockDim.x + threadIdx.x;   // 0..4095
    if (t < 2048) {  // W1 Phase-A table
        int e = t;
        int tt = e >> 9, l = (e >> 3) & 63, j = e & 7;
        int n = tt * 32 + (l & 31), h = l >> 5;
        unsigned short v = 0;
        float src = 0.0f; bool have = false;
        if (j < 5)       { src = W1[n * 5 + j]; have = true; }
        else if (j == 5) { src = b1[n];         have = true; }
        if (have) {
            unsigned int hi = rne_bf16_bits(src);
            if (h == 0) v = (unsigned short)hi;
            else        v = (unsigned short)rne_bf16_bits(src - bf16_to_f32(hi));
        }
        w1f[e] = v;
    }
    for (int e = t; e < 16 * 64 * 8; e += 4096) {    // GEMM2 table (8192 ushorts)
        int F = e >> 9, l = (e >> 3) & 63, j = e & 7;
        int mat = F >> 3, kt = F & 7;
        int tt = kt >> 1, c = kt & 1;
        int n2 = l & 31, h = l >> 5;
        int k = 32 * tt + 16 * c + 4 * h + (j & 3) + 8 * (j >> 2);
        const float* W = mat ? W22 : W21;
        frg[e] = (unsigned short)rne_bf16_bits(W[n2 * 128 + k]);
    }
}

// 1024 blocks (3/CU resident, 12 waves/CU), block = 4 waves = 512 rows;
// wave = 4 iters x 32 rows.
__global__ __launch_bounds__(BLK, 3) void barriernet_kernel(
    const float* __restrict__ x,
    const float* __restrict__ mean, const float* __restrict__ stdv,
    const float* __restrict__ b21, const float* __restrict__ b22,
    const float* __restrict__ W31, const float* __restrict__ b31,
    const float* __restrict__ W32, const float* __restrict__ b32,
    const u32x4* __restrict__ w1fg, const u32x4* __restrict__ frg,
    float* __restrict__ out, int zero)
{
    __shared__ u32x4 ldsF[1024];    // 16 GEMM2 frags x 64 lanes

    const int tid = threadIdx.x;
    #pragma unroll
    for (int i = 0; i < 4; ++i) ldsF[tid + i * BLK] = frg[tid + i * BLK];

    const int lane = tid & 63;
    const int wave = tid >> 6;
    const int R    = lane & 31;     // batch row within tile
    const int h    = lane >> 5;     // K-half / out-neuron offset bit

    // W1 Phase-A A-fragments: register-resident (16 VGPRs).
    u32x4 w1f[4];
    #pragma unroll
    for (int t = 0; t < 4; ++t) w1f[t] = w1fg[t * 64 + lane];

    // Bias / head vectors in out-neuron register order.
    f32x4 bc21[4], bc22[4], wh31[4], wh32[4];
    #pragma unroll
    for (int rq = 0; rq < 4; ++rq) {
        bc21[rq] = *(const f32x4*)(b21 + 8 * rq + 4 * h);
        bc22[rq] = *(const f32x4*)(b22 + 8 * rq + 4 * h);
        wh31[rq] = *(const f32x4*)(W31 + 8 * rq + 4 * h);
        wh32[rq] = *(const f32x4*)(W32 + 8 * rq + 4 * h);
    }

    float sm_s[5], sm_m[5];
    #pragma unroll
    for (int f = 0; f < 5; ++f) { sm_s[f] = stdv[f]; sm_m[f] = mean[f]; }
    const float b31s = b31[0], b32s = b32[0];

    __syncthreads();

    const size_t wrow0 = (size_t)blockIdx.x * 512 + wave * 128;

    // x prefetch for iter 0 (row wrow0 + R; 2x redundancy across halves)
    float4 xc4; float xc1;
    {
        const float* p = x + (wrow0 + R) * 5;
        xc4 = *(const float4*)p; xc1 = p[4];
    }

    #pragma unroll 1
    for (int it = 0; it < 4; ++it) {
        const int itn = (it < 3) ? it + 1 : 3;
        const float* pn = x + (wrow0 + itn * 32 + R) * 5;
        float4 xn4 = *(const float4*)pn;
        float  xn1 = pn[4];

        const float xf[5] = { xc4.x, xc4.y, xc4.z, xc4.w, xc1 };

        // ---- Phase-A B-fragment: {bf16(x0..x4), 1.0, 0, 0} in both halves ----
        u32x4 xd;
        xd[0] = pk_bf16(xf[0], xf[1]);
        xd[1] = pk_bf16(xf[2], xf[3]);
        xd[2] = pk_bf16(xf[4], 1.0f);
        xd[3] = 0u;
        const bf16x8 xb = __builtin_bit_cast(bf16x8, xd);

        // ---- Phase A: 4 MFMAs (32x32x16); D_t regs ARE GEMM2 B-fragments ----
        unsigned int au[8][4];
        #pragma unroll
        for (int t = 0; t < 4; ++t) {
            f32x16 z = {};
            f32x16 D = __builtin_amdgcn_mfma_f32_32x32x16_bf16(
                __builtin_bit_cast(bf16x8, w1f[t]), xb, z, 0, 0, 0);
            #pragma unroll
            for (int c = 0; c < 2; ++c)
                #pragma unroll
                for (int d = 0; d < 4; ++d)
                    au[2 * t + c][d] = pk_bf16(fmaxf(D[8 * c + 2 * d],     0.0f),
                                               fmaxf(D[8 * c + 2 * d + 1], 0.0f));
        }

        // ---- GEMM2: 16 MFMAs (32x32x16), W2 A-frags from LDS ----
        f32x16 acc21, acc22;
        #pragma unroll
        for (int rq = 0; rq < 4; ++rq)
            #pragma unroll
            for (int r = 0; r < 4; ++r) {
                acc21[rq * 4 + r] = bc21[rq][r];
                acc22[rq * 4 + r] = bc22[rq][r];
            }
        const int fz = it * zero;                  // anti-hoist for LDS reads
        #pragma unroll
        for (int kt = 0; kt < 8; ++kt) {
            u32x4 t4 = { au[kt][0], au[kt][1], au[kt][2], au[kt][3] };
            const bf16x8 b = __builtin_bit_cast(bf16x8, t4);
            const bf16x8 wa21 = __builtin_bit_cast(bf16x8, ldsF[kt * 64 + lane + fz]);
            const bf16x8 wa22 = __builtin_bit_cast(bf16x8, ldsF[(8 + kt) * 64 + lane + fz]);
            acc21 = __builtin_amdgcn_mfma_f32_32x32x16_bf16(wa21, b, acc21, 0, 0, 0);
            acc22 = __builtin_amdgcn_mfma_f32_32x32x16_bf16(wa22, b, acc22, 0, 0, 0);
        }

        // ---- Heads: 16 lane-local FMAs each + one cross-half shuffle ----
        float s31 = 0.0f, s32 = 0.0f;
        #pragma unroll
        for (int rq = 0; rq < 4; ++rq)
            #pragma unroll
            for (int r = 0; r < 4; ++r) {
                s31 = fmaf(fmaxf(acc21[rq * 4 + r], 0.0f), wh31[rq][r], s31);
                s32 = fmaf(fmaxf(acc22[rq * 4 + r], 0.0f), wh32[rq][r], s32);
            }
        s31 += __shfl_xor(s31, 32);
        s32 += __shfl_xor(s32, 32);

        // ---- Epilogue (row R; lanes 0-31 store) ----
        const float x31 = s31 + b31s;
        const float z   = s32 + b32s;
        const float x32 = 4.0f / (1.0f + __expf(-z));
        float x0[5];
        #pragma unroll
        for (int f = 0; f < 5; ++f) x0[f] = fmaf(xf[f], sm_s[f], sm_m[f]);
        const float h_ineq = (x0[1] - x0[3]) + x32 * (x0[0] - x0[2] - 1.8f * x0[3]);
        const float u_unc  = -x31;
        const float u      = (1.8f * u_unc <= h_ineq) ? u_unc : (h_ineq / 1.8f);
        if (lane < 32)
            out[wrow0 + it * 32 + R] = u;

        xc4 = xn4; xc1 = xn1;
    }
}

extern "C" void kernel_launch(void* const* d_in, const int* in_sizes, int n_in,
                              void* d_out, int out_size, void* d_ws, size_t ws_size,
                              hipStream_t stream) {
    const float* x    = (const float*)d_in[0];
    const float* mean = (const float*)d_in[1];
    const float* stdv = (const float*)d_in[2];
    const float* W1   = (const float*)d_in[3];
    const float* b1   = (const float*)d_in[4];
    const float* W21  = (const float*)d_in[5];
    const float* b21  = (const float*)d_in[6];
    const float* W22  = (const float*)d_in[7];
    const float* b22  = (const float*)d_in[8];
    const float* W31  = (const float*)d_in[9];
    const float* b31  = (const float*)d_in[10];
    const float* W32  = (const float*)d_in[11];
    const float* b32  = (const float*)d_in[12];
    float* out = (float*)d_out;

    unsigned short* w1f = (unsigned short*)d_ws;
    unsigned short* frg = (unsigned short*)((char*)d_ws + 4096);

    setup_kernel<<<16, 256, 0, stream>>>(W1, b1, W21, W22, w1f, frg);

    // 524288 rows / 512 rows-per-block = 1024 blocks (3/CU resident)
    barriernet_kernel<<<1024, BLK, 0, stream>>>(
        x, mean, stdv, b21, b22, W31, b31, W32, b32,
        (const u32x4*)w1f, (const u32x4*)frg, out, /*zero=*/0);
}